// Round 17
// baseline (180.959 us; speedup 1.0000x reference)
//
#include <hip/hip_runtime.h>
#include <hip/hip_bf16.h>
#include <math.h>
#include <stdint.h>

// Problem constants
#define N_ROWS 4096
#define IN_F   1024
#define HEAD_N 4002
#define C0_H   256
#define C0_N   16000
#define C1_H   64
#define C1_N   30257
#define CUT0   4000
#define CUT1   20000
#define HW1    384     // packed hidden width: 256 (c0) + 128 (c1 padded)

#define LOG2E 1.4426950408889634f
#define LN2   0.6931471805599453f

// sum-exp segmentation (compile-time)
#define HPAD   4096
#define C0PAD  16000
#define C1PAD  30336
#define NCT_H  32      // 128-col tiles
#define NCT_0  125
#define NCT_1  237
#define NT_H   1
#define NT_0   4
#define NT_1   8
#define NS_H   32
#define NS_0   32
#define NS_1   32

typedef __attribute__((ext_vector_type(8))) short bf16x8;
typedef __attribute__((ext_vector_type(4))) float f32x4;

__device__ __forceinline__ float exp2_fast(float x) {
    return __builtin_amdgcn_exp2f(x);
}

__device__ __forceinline__ ushort f2bf(float f) {
    uint32_t u = __builtin_bit_cast(uint32_t, f);
    uint32_t r = (u + 0x7fffu + ((u >> 16) & 1u)) >> 16;
    return (ushort)r;
}
__device__ __forceinline__ float bf2f(ushort u) {
    return __builtin_bit_cast(float, (uint32_t)u << 16);
}

__device__ __forceinline__ void gload_lds_16(const void* gsrc, void* ldst) {
    __builtin_amdgcn_global_load_lds(
        (const __attribute__((address_space(1))) void*)(uintptr_t)gsrc,
        (__attribute__((address_space(3))) void*)(uint32_t)(uintptr_t)ldst,
        16, 0, 0);
}

// ---------- fused prep: x cast + 5 transpose-casts, one dispatch ----------
__device__ __forceinline__ void castT_body(const float* __restrict__ B,
                                           ushort* __restrict__ BT,
                                           int K, int N, float scale,
                                           int n0, int k0, int tid,
                                           float (*t)[33])
{
    const int tx = tid & 31, ty = tid >> 5;
    #pragma unroll
    for (int i = 0; i < 4; ++i) {
        int n = n0 + tx;
        t[ty + i * 8][tx] = (n < N) ? B[(size_t)(k0 + ty + i * 8) * N + n] : 0.0f;
    }
    __syncthreads();
    #pragma unroll
    for (int i = 0; i < 4; ++i) {
        int n = n0 + ty + i * 8;
        BT[(size_t)n * K + k0 + tx] = f2bf(t[tx][ty + i * 8] * scale);
    }
}

__global__ __launch_bounds__(256)
void prep(const float* __restrict__ x, ushort* __restrict__ x_bf,
          const float* __restrict__ head_W, ushort* __restrict__ headWT,
          const float* __restrict__ t0_W1, const float* __restrict__ t1_W1,
          ushort* __restrict__ hW1T,
          const float* __restrict__ t0_W2, ushort* __restrict__ t0W2T,
          const float* __restrict__ t1_W2, ushort* __restrict__ t1W2T)
{
    __shared__ float t[32][33];
    const int tid = threadIdx.x;
    int id = blockIdx.x;

    if (id < 4096) {                       // x -> bf16
        int i = (id * 256 + tid) * 4;
        float4 v = *reinterpret_cast<const float4*>(x + i);
        ushort4 o;
        o.x = f2bf(v.x); o.y = f2bf(v.y); o.z = f2bf(v.z); o.w = f2bf(v.w);
        *reinterpret_cast<ushort4*>(x_bf + i) = o;
        return;
    }
    id -= 4096;
    if (id < 4096) {                       // head_W^T (scaled log2e), nx=128
        castT_body(head_W, headWT, IN_F, HEAD_N, LOG2E,
                   (id % 128) * 32, (id / 128) * 32, tid, t);
        return;
    }
    id -= 4096;
    if (id < 256) {                        // t0_W1^T, nx=8
        castT_body(t0_W1, hW1T, IN_F, C0_H, 1.0f,
                   (id % 8) * 32, (id / 8) * 32, tid, t);
        return;
    }
    id -= 256;
    if (id < 128) {                        // t1_W1^T (pad to 128 rows), nx=4
        castT_body(t1_W1, hW1T + (size_t)C0_H * IN_F, IN_F, C1_H, 1.0f,
                   (id % 4) * 32, (id / 4) * 32, tid, t);
        return;
    }
    id -= 128;
    if (id < 4000) {                       // t0_W2^T (scaled), nx=500
        castT_body(t0_W2, t0W2T, C0_H, C0_N, LOG2E,
                   (id % 500) * 32, (id / 500) * 32, tid, t);
        return;
    }
    id -= 4000;
    {                                      // t1_W2^T (scaled), nx=948
        castT_body(t1_W2, t1W2T, C1_H, C1_N, LOG2E,
                   (id % 948) * 32, (id / 948) * 32, tid, t);
    }
}

// ---------- plain GEMM (bf16 out) for hidden projections (m97 structure) ----------
__global__ __launch_bounds__(256)
void gemm_out(const ushort* __restrict__ A, int lda,
              const ushort* __restrict__ BT, int ldb, int K,
              int Nreal, ushort* __restrict__ Cout, int ldc)
{
    __shared__ ushort As[128 * 32];
    __shared__ ushort Bs[128 * 32];
    const int tid = threadIdx.x;
    const int l = tid & 63, w = tid >> 6;
    const int rowBase = blockIdx.y * 128, colBase = blockIdx.x * 128;
    const int rsel = l & 15, ksel = l >> 4;
    const int sr = l >> 2, skq = (l & 3) * 8;

    f32x4 acc[2][8];
    #pragma unroll
    for (int mi = 0; mi < 2; ++mi)
        #pragma unroll
        for (int ni = 0; ni < 8; ++ni) acc[mi][ni] = (f32x4){0.f, 0.f, 0.f, 0.f};

    for (int k0 = 0; k0 < K; k0 += 32) {
        #pragma unroll
        for (int i = 0; i < 2; ++i) {
            const int c = w + i * 4;
            gload_lds_16(A + (size_t)(rowBase + c * 16 + sr) * lda + k0 + skq,
                         (char*)As + c * 1024);
            gload_lds_16(BT + (size_t)(colBase + c * 16 + sr) * ldb + k0 + skq,
                         (char*)Bs + c * 1024);
        }
        __syncthreads();
        bf16x8 af[2], bfr[8];
        #pragma unroll
        for (int mi = 0; mi < 2; ++mi)
            af[mi] = *reinterpret_cast<const bf16x8*>(As + (w * 32 + mi * 16 + rsel) * 32 + ksel * 8);
        #pragma unroll
        for (int ni = 0; ni < 8; ++ni)
            bfr[ni] = *reinterpret_cast<const bf16x8*>(Bs + (ni * 16 + rsel) * 32 + ksel * 8);
        #pragma unroll
        for (int mi = 0; mi < 2; ++mi)
            #pragma unroll
            for (int ni = 0; ni < 8; ++ni)
                acc[mi][ni] = __builtin_amdgcn_mfma_f32_16x16x32_bf16(af[mi], bfr[ni], acc[mi][ni], 0, 0, 0);
        __syncthreads();
    }
    #pragma unroll
    for (int mi = 0; mi < 2; ++mi)
        #pragma unroll
        for (int ni = 0; ni < 8; ++ni) {
            const int col = colBase + ni * 16 + rsel;
            if (col < Nreal) {
                #pragma unroll
                for (int j = 0; j < 4; ++j) {
                    const int row = rowBase + w * 32 + mi * 16 + ksel * 4 + j;
                    Cout[(size_t)row * ldc + col] = f2bf(acc[mi][ni][j]);
                }
            }
        }
}

// ---------- sum-exp2 GEMM (head, c0): tri-buffer, ONE barrier per chunk ----------
// Chunk = 128 rows x 128 cols x 32 K. 3 buffer pairs (48 KB) -> 3 blocks/CU.
// Loop: wait vmcnt(4) -> barrier -> ISSUE(ch+2) -> compute(ch). barrier(ch)
// proves all waves finished reading buf[(ch-1)%3] == buf[(ch+2)%3], so the
// early issue is race-free and prefetch distance stays ~2 chunks.
__global__ __launch_bounds__(256, 3)
void sumexp_pipe(const ushort* __restrict__ A, int lda,
                 const ushort* __restrict__ BT, int ldb,
                 int K, int nCT, int ntiles, int Nreal,
                 float* __restrict__ ps, int nsplit)
{
    __shared__ ushort As[3][128 * 32];   // 3 x 8 KB
    __shared__ ushort Bs[3][128 * 32];   // 3 x 8 KB

    const int id = blockIdx.x;
    const int xsplit = ((id >> 8) << 3) + (id & 7);
    const int yrow   = (id & 255) >> 3;

    const int tid = threadIdx.x;
    const int l = tid & 63, w = tid >> 6;
    const int rowBase = yrow * 128;
    const int rsel = l & 15, ksel = l >> 4;

    const int kchunks = K >> 5;
    const int ct0 = xsplit * ntiles;
    const int ctn = min(ntiles, nCT - ct0);
    const int nch = ctn * kchunks;

    const int srow = l >> 2;
    const int skq = (((l & 3) ^ (srow & 3) ^ (srow >> 2)) << 3);

    f32x4 acc[2][8];
    float s_run[2][4];
    #pragma unroll
    for (int mi = 0; mi < 2; ++mi)
        #pragma unroll
        for (int j = 0; j < 4; ++j) s_run[mi][j] = 0.f;

    int i_kh = 0, i_ct = 0, issued = 0, ibuf = 0;
    #define ISSUE()                                                            \
    do {                                                                       \
        const int k0 = i_kh << 5;                                              \
        const size_t cb = (size_t)(ct0 + i_ct) << 7;                           \
        _Pragma("unroll")                                                      \
        for (int i = 0; i < 2; ++i) {                                          \
            const int c = w + i * 4;                                           \
            const int row = c * 16 + srow;                                     \
            gload_lds_16(A + (size_t)(rowBase + row) * lda + k0 + skq,         \
                         (char*)&As[ibuf][0] + c * 1024);                      \
            gload_lds_16(BT + (cb + row) * ldb + k0 + skq,                     \
                         (char*)&Bs[ibuf][0] + c * 1024);                      \
        }                                                                      \
        ++issued;                                                              \
        ibuf = (ibuf == 2) ? 0 : ibuf + 1;                                     \
        if (++i_kh == kchunks) { i_kh = 0; ++i_ct; }                           \
    } while (0)

    ISSUE();
    if (nch > 1) ISSUE();

    const int swz = ((rsel & 3) ^ (rsel >> 2)) << 3;
    int c_kh = 0;
    int c_colBase = ct0 << 7;
    int cbuf = 0;

    for (int ch = 0; ch < nch; ++ch) {
        // chunk ch's 4 loads done; chunk ch+1's 4 stay in flight.
        if (ch + 1 < nch) asm volatile("s_waitcnt vmcnt(4)" ::: "memory");
        else              asm volatile("s_waitcnt vmcnt(0)" ::: "memory");
        __builtin_amdgcn_s_barrier();
        if (issued < nch) ISSUE();   // into buf (ch+2)%3, safe per barrier(ch)

        if (c_kh == 0) {
            #pragma unroll
            for (int mi = 0; mi < 2; ++mi)
                #pragma unroll
                for (int ni = 0; ni < 8; ++ni)
                    acc[mi][ni] = (f32x4){0.f, 0.f, 0.f, 0.f};
        }

        bf16x8 af[2], bfr[8];
        #pragma unroll
        for (int mi = 0; mi < 2; ++mi)
            af[mi] = *reinterpret_cast<const bf16x8*>(
                &As[cbuf][(w * 32 + mi * 16 + rsel) * 32 + ((ksel * 8) ^ swz)]);
        #pragma unroll
        for (int ni = 0; ni < 8; ++ni)
            bfr[ni] = *reinterpret_cast<const bf16x8*>(
                &Bs[cbuf][(ni * 16 + rsel) * 32 + ((ksel * 8) ^ swz)]);
        #pragma unroll
        for (int mi = 0; mi < 2; ++mi)
            #pragma unroll
            for (int ni = 0; ni < 8; ++ni)
                acc[mi][ni] = __builtin_amdgcn_mfma_f32_16x16x32_bf16(
                    af[mi], bfr[ni], acc[mi][ni], 0, 0, 0);

        if (c_kh == kchunks - 1) {
            if (c_colBase + 128 > Nreal) {
                #pragma unroll
                for (int mi = 0; mi < 2; ++mi)
                    #pragma unroll
                    for (int ni = 0; ni < 8; ++ni) {
                        const bool ok = (c_colBase + ni * 16 + rsel) < Nreal;
                        #pragma unroll
                        for (int j = 0; j < 4; ++j)
                            s_run[mi][j] += ok ? exp2_fast(acc[mi][ni][j]) : 0.f;
                    }
            } else {
                #pragma unroll
                for (int mi = 0; mi < 2; ++mi)
                    #pragma unroll
                    for (int ni = 0; ni < 8; ++ni)
                        #pragma unroll
                        for (int j = 0; j < 4; ++j)
                            s_run[mi][j] += exp2_fast(acc[mi][ni][j]);
            }
            c_kh = 0;
            c_colBase += 128;
        } else {
            ++c_kh;
        }
        cbuf = (cbuf == 2) ? 0 : cbuf + 1;
    }
    #undef ISSUE

    #pragma unroll
    for (int mi = 0; mi < 2; ++mi)
        #pragma unroll
        for (int j = 0; j < 4; ++j) {
            float S = s_run[mi][j];
            #pragma unroll
            for (int off = 8; off; off >>= 1) S += __shfl_xor(S, off);
            if (rsel == 0) {
                const int row = rowBase + w * 32 + mi * 16 + ksel * 4 + j;
                ps[(size_t)row * nsplit + xsplit] = S;
            }
        }
}

// ---------- c1: A (K=64) in registers, B tri-buffer, ONE barrier per tile ----------
__global__ __launch_bounds__(256, 3)
void sumexp_c1(const ushort* __restrict__ A,   // h_comb + 256, lda = HW1
               const ushort* __restrict__ BT,  // t1W2T, ldb = 64
               float* __restrict__ ps)
{
    __shared__ ushort Bs[3][128 * 64];   // 3 x 16 KB

    const int id = blockIdx.x;
    const int xsplit = ((id >> 8) << 3) + (id & 7);   // 0..31
    const int yrow   = (id & 255) >> 3;               // 0..31

    const int tid = threadIdx.x;
    const int l = tid & 63, w = tid >> 6;
    const int rowBase = yrow * 128;
    const int rsel = l & 15, ksel = l >> 4;

    const int ct0 = xsplit * NT_1;
    const int ctn = min(NT_1, NCT_1 - ct0);           // may be <= 0

    bf16x8 af[2][2];
    #pragma unroll
    for (int kk = 0; kk < 2; ++kk)
        #pragma unroll
        for (int mi = 0; mi < 2; ++mi)
            af[kk][mi] = *reinterpret_cast<const bf16x8*>(
                A + (size_t)(rowBase + w * 32 + mi * 16 + rsel) * HW1 +
                kk * 32 + ksel * 8);

    const int srow8 = l >> 3;
    const int skq = (((l & 7) ^ srow8) << 3);

    float s_run[2][4];
    #pragma unroll
    for (int mi = 0; mi < 2; ++mi)
        #pragma unroll
        for (int j = 0; j < 4; ++j) s_run[mi][j] = 0.f;

    if (ctn > 0) {
        int issued = 0, ibuf = 0;
        #define ISSUE_B()                                                      \
        do {                                                                   \
            const size_t cb = (size_t)(ct0 + issued) << 7;                     \
            _Pragma("unroll")                                                  \
            for (int i = 0; i < 4; ++i) {                                      \
                const int c = w * 4 + i;                                       \
                gload_lds_16(BT + (cb + c * 8 + srow8) * 64 + skq,             \
                             (char*)&Bs[ibuf][0] + c * 1024);                  \
            }                                                                  \
            ++issued;                                                          \
            ibuf = (ibuf == 2) ? 0 : ibuf + 1;                                 \
        } while (0)

        ISSUE_B();
        if (ctn > 1) ISSUE_B();

        const int bswz = rsel & 7;
        int cbuf = 0;

        for (int t = 0; t < ctn; ++t) {
            if (t + 1 < ctn) asm volatile("s_waitcnt vmcnt(4)" ::: "memory");
            else             asm volatile("s_waitcnt vmcnt(0)" ::: "memory");
            __builtin_amdgcn_s_barrier();
            if (issued < ctn) ISSUE_B();

            f32x4 acc[2][8];
            #pragma unroll
            for (int mi = 0; mi < 2; ++mi)
                #pragma unroll
                for (int ni = 0; ni < 8; ++ni)
                    acc[mi][ni] = (f32x4){0.f, 0.f, 0.f, 0.f};

            #pragma unroll
            for (int kk = 0; kk < 2; ++kk) {
                bf16x8 bfr[8];
                #pragma unroll
                for (int ni = 0; ni < 8; ++ni)
                    bfr[ni] = *reinterpret_cast<const bf16x8*>(
                        &Bs[cbuf][(ni * 16 + rsel) * 64 +
                                  (((kk * 4 + ksel) ^ bswz) << 3)]);
                #pragma unroll
                for (int mi = 0; mi < 2; ++mi)
                    #pragma unroll
                    for (int ni = 0; ni < 8; ++ni)
                        acc[mi][ni] = __builtin_amdgcn_mfma_f32_16x16x32_bf16(
                            af[kk][mi], bfr[ni], acc[mi][ni], 0, 0, 0);
            }

            const int colBase = (ct0 + t) << 7;
            if (colBase + 128 > C1_N) {
                #pragma unroll
                for (int mi = 0; mi < 2; ++mi)
                    #pragma unroll
                    for (int ni = 0; ni < 8; ++ni) {
                        const bool ok = (colBase + ni * 16 + rsel) < C1_N;
                        #pragma unroll
                        for (int j = 0; j < 4; ++j)
                            s_run[mi][j] += ok ? exp2_fast(acc[mi][ni][j]) : 0.f;
                    }
            } else {
                #pragma unroll
                for (int mi = 0; mi < 2; ++mi)
                    #pragma unroll
                    for (int ni = 0; ni < 8; ++ni)
                        #pragma unroll
                        for (int j = 0; j < 4; ++j)
                            s_run[mi][j] += exp2_fast(acc[mi][ni][j]);
            }
            cbuf = (cbuf == 2) ? 0 : cbuf + 1;
        }
        #undef ISSUE_B
    }

    #pragma unroll
    for (int mi = 0; mi < 2; ++mi)
        #pragma unroll
        for (int j = 0; j < 4; ++j) {
            float S = s_run[mi][j];
            #pragma unroll
            for (int off = 8; off; off >>= 1) S += __shfl_xor(S, off);
            if (rsel == 0) {
                const int row = rowBase + w * 32 + mi * 16 + ksel * 4 + j;
                ps[(size_t)row * NS_1 + xsplit] = S;
            }
        }
}

// ---------- fused gather + combine: one wave per row ----------
__global__ __launch_bounds__(256)
void gather_combine(const ushort* __restrict__ x_bf,
                    const ushort* __restrict__ h_comb,
                    const ushort* __restrict__ headWT,
                    const ushort* __restrict__ t0W2T,
                    const ushort* __restrict__ t1W2T,
                    const int* __restrict__ target,
                    const float* __restrict__ ps_h,
                    const float* __restrict__ ps_0,
                    const float* __restrict__ ps_1,
                    float* __restrict__ out)
{
    const int r = blockIdx.x * 4 + (threadIdx.x >> 6);
    const int l = threadIdx.x & 63;
    const int t = target[r];

    const int gh = (t < CUT0) ? t : ((t < CUT1) ? CUT0 : CUT0 + 1);
    const ushort* xr = x_bf + (size_t)r * IN_F + l * 16;
    const ushort* wr = headWT + (size_t)gh * IN_F + l * 16;
    float s = 0.f;
    #pragma unroll
    for (int v = 0; v < 2; ++v) {
        ushort4 xa = *reinterpret_cast<const ushort4*>(xr + v * 8);
        ushort4 xb = *reinterpret_cast<const ushort4*>(xr + v * 8 + 4);
        ushort4 wa = *reinterpret_cast<const ushort4*>(wr + v * 8);
        ushort4 wb = *reinterpret_cast<const ushort4*>(wr + v * 8 + 4);
        s += bf2f(xa.x) * bf2f(wa.x) + bf2f(xa.y) * bf2f(wa.y)
           + bf2f(xa.z) * bf2f(wa.z) + bf2f(xa.w) * bf2f(wa.w)
           + bf2f(xb.x) * bf2f(wb.x) + bf2f(xb.y) * bf2f(wb.y)
           + bf2f(xb.z) * bf2f(wb.z) + bf2f(xb.w) * bf2f(wb.w);
    }
    #pragma unroll
    for (int off = 32; off; off >>= 1) s += __shfl_xor(s, off);

    float Sh = (l < NS_H) ? ps_h[(size_t)r * NS_H + l] : 0.f;
    #pragma unroll
    for (int off = 32; off; off >>= 1) Sh += __shfl_xor(Sh, off);

    float o = s * LN2 - __logf(Sh);

    if (t >= CUT0) {
        float c = 0.f;
        if (t < CUT1) {
            const ushort* hr = h_comb + (size_t)r * HW1 + l * 4;
            const ushort* vr = t0W2T + (size_t)(t - CUT0) * C0_H + l * 4;
            ushort4 ha = *reinterpret_cast<const ushort4*>(hr);
            ushort4 va = *reinterpret_cast<const ushort4*>(vr);
            c = bf2f(ha.x) * bf2f(va.x) + bf2f(ha.y) * bf2f(va.y)
              + bf2f(ha.z) * bf2f(va.z) + bf2f(ha.w) * bf2f(va.w);
        } else {
            c = bf2f(h_comb[(size_t)r * HW1 + C0_H + l]) *
                bf2f(t1W2T[(size_t)(t - CUT1) * C1_H + l]);
        }
        #pragma unroll
        for (int off = 32; off; off >>= 1) c += __shfl_xor(c, off);

        float Sc;
        if (t < CUT1) Sc = (l < NS_0) ? ps_0[(size_t)r * NS_0 + l] : 0.f;
        else          Sc = (l < NS_1) ? ps_1[(size_t)r * NS_1 + l] : 0.f;
        #pragma unroll
        for (int off = 32; off; off >>= 1) Sc += __shfl_xor(Sc, off);

        o += c * LN2 - __logf(Sc);
    }
    if (l == 0) out[r] = o;
}

__global__ __launch_bounds__(256)
void finalize_loss(const float* __restrict__ out, float* __restrict__ loss)
{
    float s = 0.f;
    for (int r = threadIdx.x; r < N_ROWS; r += 256) s += out[r];
    #pragma unroll
    for (int off = 32; off; off >>= 1) s += __shfl_xor(s, off);
    __shared__ float red[4];
    if ((threadIdx.x & 63) == 0) red[threadIdx.x >> 6] = s;
    __syncthreads();
    if (threadIdx.x == 0)
        loss[0] = -(red[0] + red[1] + red[2] + red[3]) / (float)N_ROWS;
}

extern "C" void kernel_launch(void* const* d_in, const int* in_sizes, int n_in,
                              void* d_out, int out_size, void* d_ws, size_t ws_size,
                              hipStream_t stream)
{
    const float* x      = (const float*)d_in[0];
    const int*   target = (const int*)  d_in[1];
    const float* head_W = (const float*)d_in[2];
    const float* t0_W1  = (const float*)d_in[3];
    const float* t0_W2  = (const float*)d_in[4];
    const float* t1_W1  = (const float*)d_in[5];
    const float* t1_W2  = (const float*)d_in[6];
    float* out = (float*)d_out;

    ushort* us = (ushort*)d_ws;
    ushort* x_bf   = us; us += (size_t)N_ROWS * IN_F;
    ushort* headWT = us; us += (size_t)HPAD * IN_F;
    ushort* hW1T   = us; us += (size_t)HW1 * IN_F;
    ushort* t0W2T  = us; us += (size_t)C0PAD * C0_H;
    ushort* t1W2T  = us; us += (size_t)C1PAD * C1_H;
    ushort* h_comb = us; us += (size_t)N_ROWS * HW1;

    float* ws   = (float*)us;
    float* ps_h = ws; ws += (size_t)N_ROWS * NS_H;
    float* ps_0 = ws; ws += (size_t)N_ROWS * NS_0;
    float* ps_1 = ws; ws += (size_t)N_ROWS * NS_1;

    const dim3 blk(256);

    // 1) all casts + transposes
    hipLaunchKernelGGL(prep, dim3(14472), blk, 0, stream,
                       x, x_bf, head_W, headWT, t0_W1, t1_W1, hW1T,
                       t0_W2, t0W2T, t1_W2, t1W2T);

    // 2) packed hidden projections: h_comb[:, :320] = x @ [t0_W1 | t1_W1]
    hipLaunchKernelGGL(gemm_out, dim3(HW1 / 128, N_ROWS / 128), blk, 0, stream,
                       x_bf, IN_F, hW1T, IN_F, IN_F, C0_H + C1_H, h_comb, HW1);

    // 3) sum-exp GEMMs (separate dispatches: homogeneous L2 locality)
    hipLaunchKernelGGL(sumexp_pipe, dim3(NS_H * 32), blk, 0, stream,
                       x_bf, IN_F, headWT, IN_F, IN_F, NCT_H, NT_H, HEAD_N, ps_h, NS_H);
    hipLaunchKernelGGL(sumexp_pipe, dim3(NS_0 * 32), blk, 0, stream,
                       h_comb, HW1, t0W2T, C0_H, C0_H, NCT_0, NT_0, C0_N, ps_0, NS_0);
    hipLaunchKernelGGL(sumexp_c1, dim3(NS_1 * 32), blk, 0, stream,
                       h_comb + C0_H, t1W2T, ps_1);

    // 4) gather + combine, 5) loss
    hipLaunchKernelGGL(gather_combine, dim3(N_ROWS / 4), blk, 0, stream,
                       x_bf, h_comb, headWT, t0W2T, t1W2T, target,
                       ps_h, ps_0, ps_1, out);
    hipLaunchKernelGGL(finalize_loss, dim3(1), blk, 0, stream, out, out + N_ROWS);
}

// Round 18
// 169.659 us; speedup vs baseline: 1.0666x; 1.0666x over previous
//
#include <hip/hip_runtime.h>
#include <hip/hip_bf16.h>
#include <math.h>
#include <stdint.h>

// Problem constants
#define N_ROWS 4096
#define IN_F   1024
#define HEAD_N 4002
#define C0_H   256
#define C0_N   16000
#define C1_H   64
#define C1_N   30257
#define CUT0   4000
#define CUT1   20000
#define HW1    384     // packed hidden width: 256 (c0) + 128 (c1 padded)

#define LOG2E 1.4426950408889634f
#define LN2   0.6931471805599453f

// sum-exp segmentation (compile-time)
#define HPAD   4096
#define C0PAD  16000
#define C1PAD  30336
#define NCT_H  32      // 128-col tiles
#define NCT_0  125
#define NCT_1  237
#define NT_H   1
#define NT_0   4
#define NT_1   8
#define NS_H   32
#define NS_0   32
#define NS_1   32

typedef __attribute__((ext_vector_type(8))) short bf16x8;
typedef __attribute__((ext_vector_type(4))) float f32x4;

__device__ __forceinline__ float exp2_fast(float x) {
    return __builtin_amdgcn_exp2f(x);
}

__device__ __forceinline__ ushort f2bf(float f) {
    uint32_t u = __builtin_bit_cast(uint32_t, f);
    uint32_t r = (u + 0x7fffu + ((u >> 16) & 1u)) >> 16;
    return (ushort)r;
}
__device__ __forceinline__ float bf2f(ushort u) {
    return __builtin_bit_cast(float, (uint32_t)u << 16);
}

__device__ __forceinline__ void gload_lds_16(const void* gsrc, void* ldst) {
    __builtin_amdgcn_global_load_lds(
        (const __attribute__((address_space(1))) void*)(uintptr_t)gsrc,
        (__attribute__((address_space(3))) void*)(uint32_t)(uintptr_t)ldst,
        16, 0, 0);
}

// ---------- fused prep: x cast + 5 transpose-casts, one dispatch ----------
__device__ __forceinline__ void castT_body(const float* __restrict__ B,
                                           ushort* __restrict__ BT,
                                           int K, int N, float scale,
                                           int n0, int k0, int tid,
                                           float (*t)[33])
{
    const int tx = tid & 31, ty = tid >> 5;
    #pragma unroll
    for (int i = 0; i < 4; ++i) {
        int n = n0 + tx;
        t[ty + i * 8][tx] = (n < N) ? B[(size_t)(k0 + ty + i * 8) * N + n] : 0.0f;
    }
    __syncthreads();
    #pragma unroll
    for (int i = 0; i < 4; ++i) {
        int n = n0 + ty + i * 8;
        BT[(size_t)n * K + k0 + tx] = f2bf(t[tx][ty + i * 8] * scale);
    }
}

__global__ __launch_bounds__(256)
void prep(const float* __restrict__ x, ushort* __restrict__ x_bf,
          const float* __restrict__ head_W, ushort* __restrict__ headWT,
          const float* __restrict__ t0_W1, const float* __restrict__ t1_W1,
          ushort* __restrict__ hW1T,
          const float* __restrict__ t0_W2, ushort* __restrict__ t0W2T,
          const float* __restrict__ t1_W2, ushort* __restrict__ t1W2T)
{
    __shared__ float t[32][33];
    const int tid = threadIdx.x;
    int id = blockIdx.x;

    if (id < 4096) {                       // x -> bf16
        int i = (id * 256 + tid) * 4;
        float4 v = *reinterpret_cast<const float4*>(x + i);
        ushort4 o;
        o.x = f2bf(v.x); o.y = f2bf(v.y); o.z = f2bf(v.z); o.w = f2bf(v.w);
        *reinterpret_cast<ushort4*>(x_bf + i) = o;
        return;
    }
    id -= 4096;
    if (id < 4096) {                       // head_W^T (scaled log2e), nx=128
        castT_body(head_W, headWT, IN_F, HEAD_N, LOG2E,
                   (id % 128) * 32, (id / 128) * 32, tid, t);
        return;
    }
    id -= 4096;
    if (id < 256) {                        // t0_W1^T, nx=8
        castT_body(t0_W1, hW1T, IN_F, C0_H, 1.0f,
                   (id % 8) * 32, (id / 8) * 32, tid, t);
        return;
    }
    id -= 256;
    if (id < 128) {                        // t1_W1^T (pad to 128 rows), nx=4
        castT_body(t1_W1, hW1T + (size_t)C0_H * IN_F, IN_F, C1_H, 1.0f,
                   (id % 4) * 32, (id / 4) * 32, tid, t);
        return;
    }
    id -= 128;
    if (id < 4000) {                       // t0_W2^T (scaled), nx=500
        castT_body(t0_W2, t0W2T, C0_H, C0_N, LOG2E,
                   (id % 500) * 32, (id / 500) * 32, tid, t);
        return;
    }
    id -= 4000;
    {                                      // t1_W2^T (scaled), nx=948
        castT_body(t1_W2, t1W2T, C1_H, C1_N, LOG2E,
                   (id % 948) * 32, (id / 948) * 32, tid, t);
    }
}

// ---------- plain GEMM (bf16 out) for hidden projections (m97 structure) ----------
__global__ __launch_bounds__(256)
void gemm_out(const ushort* __restrict__ A, int lda,
              const ushort* __restrict__ BT, int ldb, int K,
              int Nreal, ushort* __restrict__ Cout, int ldc)
{
    __shared__ ushort As[128 * 32];
    __shared__ ushort Bs[128 * 32];
    const int tid = threadIdx.x;
    const int l = tid & 63, w = tid >> 6;
    const int rowBase = blockIdx.y * 128, colBase = blockIdx.x * 128;
    const int rsel = l & 15, ksel = l >> 4;
    const int sr = l >> 2, skq = (l & 3) * 8;

    f32x4 acc[2][8];
    #pragma unroll
    for (int mi = 0; mi < 2; ++mi)
        #pragma unroll
        for (int ni = 0; ni < 8; ++ni) acc[mi][ni] = (f32x4){0.f, 0.f, 0.f, 0.f};

    for (int k0 = 0; k0 < K; k0 += 32) {
        #pragma unroll
        for (int i = 0; i < 2; ++i) {
            const int c = w + i * 4;
            gload_lds_16(A + (size_t)(rowBase + c * 16 + sr) * lda + k0 + skq,
                         (char*)As + c * 1024);
            gload_lds_16(BT + (size_t)(colBase + c * 16 + sr) * ldb + k0 + skq,
                         (char*)Bs + c * 1024);
        }
        __syncthreads();
        bf16x8 af[2], bfr[8];
        #pragma unroll
        for (int mi = 0; mi < 2; ++mi)
            af[mi] = *reinterpret_cast<const bf16x8*>(As + (w * 32 + mi * 16 + rsel) * 32 + ksel * 8);
        #pragma unroll
        for (int ni = 0; ni < 8; ++ni)
            bfr[ni] = *reinterpret_cast<const bf16x8*>(Bs + (ni * 16 + rsel) * 32 + ksel * 8);
        #pragma unroll
        for (int mi = 0; mi < 2; ++mi)
            #pragma unroll
            for (int ni = 0; ni < 8; ++ni)
                acc[mi][ni] = __builtin_amdgcn_mfma_f32_16x16x32_bf16(af[mi], bfr[ni], acc[mi][ni], 0, 0, 0);
        __syncthreads();
    }
    #pragma unroll
    for (int mi = 0; mi < 2; ++mi)
        #pragma unroll
        for (int ni = 0; ni < 8; ++ni) {
            const int col = colBase + ni * 16 + rsel;
            if (col < Nreal) {
                #pragma unroll
                for (int j = 0; j < 4; ++j) {
                    const int row = rowBase + w * 32 + mi * 16 + ksel * 4 + j;
                    Cout[(size_t)row * ldc + col] = f2bf(acc[mi][ni][j]);
                }
            }
        }
}

// ---------- pipelined streaming sum-exp2 GEMM (head, c0): R14/R16 config ----------
// Chunk = 128 rows x 128 cols x 32 K. 32 KB LDS dbuf, depth-2 counted
// vmcnt(4), raw s_barrier, 4 blocks/CU (NEVER 5: 64-reg acc spills — R15;
// NEVER tri-buffer 48 KB: occupancy loss beats barrier gain — R17).
// B pre-scaled by log2e -> bare v_exp_f32. XCD-bijective 1-D grid decode.
__global__ __launch_bounds__(256, 4)
void sumexp_pipe(const ushort* __restrict__ A, int lda,
                 const ushort* __restrict__ BT, int ldb,
                 int K, int nCT, int ntiles, int Nreal,
                 float* __restrict__ ps, int nsplit)
{
    __shared__ ushort As[2][128 * 32];   // 2 x 8 KB
    __shared__ ushort Bs[2][128 * 32];   // 2 x 8 KB

    const int id = blockIdx.x;
    const int xsplit = ((id >> 8) << 3) + (id & 7);
    const int yrow   = (id & 255) >> 3;

    const int tid = threadIdx.x;
    const int l = tid & 63, w = tid >> 6;
    const int rowBase = yrow * 128;
    const int rsel = l & 15, ksel = l >> 4;

    const int kchunks = K >> 5;
    const int ct0 = xsplit * ntiles;
    const int ctn = min(ntiles, nCT - ct0);
    const int nch = ctn * kchunks;

    const int srow = l >> 2;
    const int skq = (((l & 3) ^ (srow & 3) ^ (srow >> 2)) << 3);

    f32x4 acc[2][8];
    float s_run[2][4];
    #pragma unroll
    for (int mi = 0; mi < 2; ++mi)
        #pragma unroll
        for (int j = 0; j < 4; ++j) s_run[mi][j] = 0.f;

    int i_kh = 0, i_ct = 0, issued = 0;
    #define ISSUE()                                                            \
    do {                                                                       \
        const int buf = issued & 1;                                            \
        const int k0 = i_kh << 5;                                              \
        const size_t cb = (size_t)(ct0 + i_ct) << 7;                           \
        _Pragma("unroll")                                                      \
        for (int i = 0; i < 2; ++i) {                                          \
            const int c = w + i * 4;                                           \
            const int row = c * 16 + srow;                                     \
            gload_lds_16(A + (size_t)(rowBase + row) * lda + k0 + skq,         \
                         (char*)&As[buf][0] + c * 1024);                       \
            gload_lds_16(BT + (cb + row) * ldb + k0 + skq,                     \
                         (char*)&Bs[buf][0] + c * 1024);                       \
        }                                                                      \
        ++issued;                                                              \
        if (++i_kh == kchunks) { i_kh = 0; ++i_ct; }                           \
    } while (0)

    ISSUE();
    if (nch > 1) ISSUE();

    const int swz = ((rsel & 3) ^ (rsel >> 2)) << 3;
    int c_kh = 0;
    int c_colBase = ct0 << 7;

    for (int ch = 0; ch < nch; ++ch) {
        if (ch + 1 < nch) asm volatile("s_waitcnt vmcnt(4)" ::: "memory");
        else              asm volatile("s_waitcnt vmcnt(0)" ::: "memory");
        __builtin_amdgcn_s_barrier();

        if (c_kh == 0) {
            #pragma unroll
            for (int mi = 0; mi < 2; ++mi)
                #pragma unroll
                for (int ni = 0; ni < 8; ++ni)
                    acc[mi][ni] = (f32x4){0.f, 0.f, 0.f, 0.f};
        }

        const int buf = ch & 1;
        bf16x8 af[2], bfr[8];
        #pragma unroll
        for (int mi = 0; mi < 2; ++mi)
            af[mi] = *reinterpret_cast<const bf16x8*>(
                &As[buf][(w * 32 + mi * 16 + rsel) * 32 + ((ksel * 8) ^ swz)]);
        #pragma unroll
        for (int ni = 0; ni < 8; ++ni)
            bfr[ni] = *reinterpret_cast<const bf16x8*>(
                &Bs[buf][(ni * 16 + rsel) * 32 + ((ksel * 8) ^ swz)]);
        #pragma unroll
        for (int mi = 0; mi < 2; ++mi)
            #pragma unroll
            for (int ni = 0; ni < 8; ++ni)
                acc[mi][ni] = __builtin_amdgcn_mfma_f32_16x16x32_bf16(
                    af[mi], bfr[ni], acc[mi][ni], 0, 0, 0);

        __builtin_amdgcn_s_barrier();
        if (issued < nch) ISSUE();

        if (c_kh == kchunks - 1) {
            if (c_colBase + 128 > Nreal) {
                #pragma unroll
                for (int mi = 0; mi < 2; ++mi)
                    #pragma unroll
                    for (int ni = 0; ni < 8; ++ni) {
                        const bool ok = (c_colBase + ni * 16 + rsel) < Nreal;
                        #pragma unroll
                        for (int j = 0; j < 4; ++j)
                            s_run[mi][j] += ok ? exp2_fast(acc[mi][ni][j]) : 0.f;
                    }
            } else {
                #pragma unroll
                for (int mi = 0; mi < 2; ++mi)
                    #pragma unroll
                    for (int ni = 0; ni < 8; ++ni)
                        #pragma unroll
                        for (int j = 0; j < 4; ++j)
                            s_run[mi][j] += exp2_fast(acc[mi][ni][j]);
            }
            c_kh = 0;
            c_colBase += 128;
        } else {
            ++c_kh;
        }
    }
    #undef ISSUE

    #pragma unroll
    for (int mi = 0; mi < 2; ++mi)
        #pragma unroll
        for (int j = 0; j < 4; ++j) {
            float S = s_run[mi][j];
            #pragma unroll
            for (int off = 8; off; off >>= 1) S += __shfl_xor(S, off);
            if (rsel == 0) {
                const int row = rowBase + w * 32 + mi * 16 + ksel * 4 + j;
                ps[(size_t)row * nsplit + xsplit] = S;
            }
        }
}

// ---------- c1 specialization: A (K=64) in registers, stream B only ----------
// Per block: af = 4x bf16x8 loaded once from global h1. Tile = whole K in one
// 16 KB B buffer (128-B rows, 8-slot XOR swizzle), dbuf -> 2 barriers per
// tile, depth-2 vmcnt(4). Grid 1024, XCD decode. ~36 us measured (R15/R16).
__global__ __launch_bounds__(256, 3)
void sumexp_c1(const ushort* __restrict__ A,   // h_comb + 256, lda = HW1
               const ushort* __restrict__ BT,  // t1W2T, ldb = 64
               float* __restrict__ ps)
{
    __shared__ ushort Bs[2][128 * 64];   // 2 x 16 KB

    const int id = blockIdx.x;
    const int xsplit = ((id >> 8) << 3) + (id & 7);   // 0..31
    const int yrow   = (id & 255) >> 3;               // 0..31

    const int tid = threadIdx.x;
    const int l = tid & 63, w = tid >> 6;
    const int rowBase = yrow * 128;
    const int rsel = l & 15, ksel = l >> 4;

    const int ct0 = xsplit * NT_1;
    const int ctn = min(NT_1, NCT_1 - ct0);           // may be <= 0

    // A fragments for the whole block lifetime: [kk][mi]
    bf16x8 af[2][2];
    #pragma unroll
    for (int kk = 0; kk < 2; ++kk)
        #pragma unroll
        for (int mi = 0; mi < 2; ++mi)
            af[kk][mi] = *reinterpret_cast<const bf16x8*>(
                A + (size_t)(rowBase + w * 32 + mi * 16 + rsel) * HW1 +
                kk * 32 + ksel * 8);

    // B staging: 1 KB piece = 8 rows x 128 B. Lane l -> row l>>3, slot l&7;
    // source slot pre-swizzled with row&7.
    const int srow8 = l >> 3;
    const int skq = (((l & 7) ^ srow8) << 3);   // element offset in row

    float s_run[2][4];
    #pragma unroll
    for (int mi = 0; mi < 2; ++mi)
        #pragma unroll
        for (int j = 0; j < 4; ++j) s_run[mi][j] = 0.f;

    if (ctn > 0) {
        int issued = 0;
        #define ISSUE_B()                                                      \
        do {                                                                   \
            const int buf = issued & 1;                                        \
            const size_t cb = (size_t)(ct0 + issued) << 7;                     \
            _Pragma("unroll")                                                  \
            for (int i = 0; i < 4; ++i) {                                      \
                const int c = w * 4 + i;                                       \
                gload_lds_16(BT + (cb + c * 8 + srow8) * 64 + skq,             \
                             (char*)&Bs[buf][0] + c * 1024);                   \
            }                                                                  \
            ++issued;                                                          \
        } while (0)

        ISSUE_B();
        if (ctn > 1) ISSUE_B();

        const int bswz = rsel & 7;

        for (int t = 0; t < ctn; ++t) {
            if (t + 1 < ctn) asm volatile("s_waitcnt vmcnt(4)" ::: "memory");
            else             asm volatile("s_waitcnt vmcnt(0)" ::: "memory");
            __builtin_amdgcn_s_barrier();

            f32x4 acc[2][8];
            #pragma unroll
            for (int mi = 0; mi < 2; ++mi)
                #pragma unroll
                for (int ni = 0; ni < 8; ++ni)
                    acc[mi][ni] = (f32x4){0.f, 0.f, 0.f, 0.f};

            const int buf = t & 1;
            #pragma unroll
            for (int kk = 0; kk < 2; ++kk) {
                bf16x8 bfr[8];
                #pragma unroll
                for (int ni = 0; ni < 8; ++ni)
                    bfr[ni] = *reinterpret_cast<const bf16x8*>(
                        &Bs[buf][(ni * 16 + rsel) * 64 +
                                 (((kk * 4 + ksel) ^ bswz) << 3)]);
                #pragma unroll
                for (int mi = 0; mi < 2; ++mi)
                    #pragma unroll
                    for (int ni = 0; ni < 8; ++ni)
                        acc[mi][ni] = __builtin_amdgcn_mfma_f32_16x16x32_bf16(
                            af[kk][mi], bfr[ni], acc[mi][ni], 0, 0, 0);
            }

            __builtin_amdgcn_s_barrier();
            if (issued < ctn) ISSUE_B();

            const int colBase = (ct0 + t) << 7;
            if (colBase + 128 > C1_N) {
                #pragma unroll
                for (int mi = 0; mi < 2; ++mi)
                    #pragma unroll
                    for (int ni = 0; ni < 8; ++ni) {
                        const bool ok = (colBase + ni * 16 + rsel) < C1_N;
                        #pragma unroll
                        for (int j = 0; j < 4; ++j)
                            s_run[mi][j] += ok ? exp2_fast(acc[mi][ni][j]) : 0.f;
                    }
            } else {
                #pragma unroll
                for (int mi = 0; mi < 2; ++mi)
                    #pragma unroll
                    for (int ni = 0; ni < 8; ++ni)
                        #pragma unroll
                        for (int j = 0; j < 4; ++j)
                            s_run[mi][j] += exp2_fast(acc[mi][ni][j]);
            }
        }
        #undef ISSUE_B
    }

    #pragma unroll
    for (int mi = 0; mi < 2; ++mi)
        #pragma unroll
        for (int j = 0; j < 4; ++j) {
            float S = s_run[mi][j];
            #pragma unroll
            for (int off = 8; off; off >>= 1) S += __shfl_xor(S, off);
            if (rsel == 0) {
                const int row = rowBase + w * 32 + mi * 16 + ksel * 4 + j;
                ps[(size_t)row * NS_1 + xsplit] = S;
            }
        }
}

// ---------- fused gather + combine: one wave per row ----------
__global__ __launch_bounds__(256)
void gather_combine(const ushort* __restrict__ x_bf,
                    const ushort* __restrict__ h_comb,
                    const ushort* __restrict__ headWT,
                    const ushort* __restrict__ t0W2T,
                    const ushort* __restrict__ t1W2T,
                    const int* __restrict__ target,
                    const float* __restrict__ ps_h,
                    const float* __restrict__ ps_0,
                    const float* __restrict__ ps_1,
                    float* __restrict__ out)
{
    const int r = blockIdx.x * 4 + (threadIdx.x >> 6);
    const int l = threadIdx.x & 63;
    const int t = target[r];

    const int gh = (t < CUT0) ? t : ((t < CUT1) ? CUT0 : CUT0 + 1);
    const ushort* xr = x_bf + (size_t)r * IN_F + l * 16;
    const ushort* wr = headWT + (size_t)gh * IN_F + l * 16;
    float s = 0.f;
    #pragma unroll
    for (int v = 0; v < 2; ++v) {
        ushort4 xa = *reinterpret_cast<const ushort4*>(xr + v * 8);
        ushort4 xb = *reinterpret_cast<const ushort4*>(xr + v * 8 + 4);
        ushort4 wa = *reinterpret_cast<const ushort4*>(wr + v * 8);
        ushort4 wb = *reinterpret_cast<const ushort4*>(wr + v * 8 + 4);
        s += bf2f(xa.x) * bf2f(wa.x) + bf2f(xa.y) * bf2f(wa.y)
           + bf2f(xa.z) * bf2f(wa.z) + bf2f(xa.w) * bf2f(wa.w)
           + bf2f(xb.x) * bf2f(wb.x) + bf2f(xb.y) * bf2f(wb.y)
           + bf2f(xb.z) * bf2f(wb.z) + bf2f(xb.w) * bf2f(wb.w);
    }
    #pragma unroll
    for (int off = 32; off; off >>= 1) s += __shfl_xor(s, off);

    float Sh = (l < NS_H) ? ps_h[(size_t)r * NS_H + l] : 0.f;
    #pragma unroll
    for (int off = 32; off; off >>= 1) Sh += __shfl_xor(Sh, off);

    float o = s * LN2 - __logf(Sh);

    if (t >= CUT0) {
        float c = 0.f;
        if (t < CUT1) {
            const ushort* hr = h_comb + (size_t)r * HW1 + l * 4;
            const ushort* vr = t0W2T + (size_t)(t - CUT0) * C0_H + l * 4;
            ushort4 ha = *reinterpret_cast<const ushort4*>(hr);
            ushort4 va = *reinterpret_cast<const ushort4*>(vr);
            c = bf2f(ha.x) * bf2f(va.x) + bf2f(ha.y) * bf2f(va.y)
              + bf2f(ha.z) * bf2f(va.z) + bf2f(ha.w) * bf2f(va.w);
        } else {
            c = bf2f(h_comb[(size_t)r * HW1 + C0_H + l]) *
                bf2f(t1W2T[(size_t)(t - CUT1) * C1_H + l]);
        }
        #pragma unroll
        for (int off = 32; off; off >>= 1) c += __shfl_xor(c, off);

        float Sc;
        if (t < CUT1) Sc = (l < NS_0) ? ps_0[(size_t)r * NS_0 + l] : 0.f;
        else          Sc = (l < NS_1) ? ps_1[(size_t)r * NS_1 + l] : 0.f;
        #pragma unroll
        for (int off = 32; off; off >>= 1) Sc += __shfl_xor(Sc, off);

        o += c * LN2 - __logf(Sc);
    }
    if (l == 0) out[r] = o;
}

__global__ __launch_bounds__(256)
void finalize_loss(const float* __restrict__ out, float* __restrict__ loss)
{
    float s = 0.f;
    for (int r = threadIdx.x; r < N_ROWS; r += 256) s += out[r];
    #pragma unroll
    for (int off = 32; off; off >>= 1) s += __shfl_xor(s, off);
    __shared__ float red[4];
    if ((threadIdx.x & 63) == 0) red[threadIdx.x >> 6] = s;
    __syncthreads();
    if (threadIdx.x == 0)
        loss[0] = -(red[0] + red[1] + red[2] + red[3]) / (float)N_ROWS;
}

extern "C" void kernel_launch(void* const* d_in, const int* in_sizes, int n_in,
                              void* d_out, int out_size, void* d_ws, size_t ws_size,
                              hipStream_t stream)
{
    const float* x      = (const float*)d_in[0];
    const int*   target = (const int*)  d_in[1];
    const float* head_W = (const float*)d_in[2];
    const float* t0_W1  = (const float*)d_in[3];
    const float* t0_W2  = (const float*)d_in[4];
    const float* t1_W1  = (const float*)d_in[5];
    const float* t1_W2  = (const float*)d_in[6];
    float* out = (float*)d_out;

    ushort* us = (ushort*)d_ws;
    ushort* x_bf   = us; us += (size_t)N_ROWS * IN_F;
    ushort* headWT = us; us += (size_t)HPAD * IN_F;
    ushort* hW1T   = us; us += (size_t)HW1 * IN_F;
    ushort* t0W2T  = us; us += (size_t)C0PAD * C0_H;
    ushort* t1W2T  = us; us += (size_t)C1PAD * C1_H;
    ushort* h_comb = us; us += (size_t)N_ROWS * HW1;

    float* ws   = (float*)us;
    float* ps_h = ws; ws += (size_t)N_ROWS * NS_H;
    float* ps_0 = ws; ws += (size_t)N_ROWS * NS_0;
    float* ps_1 = ws; ws += (size_t)N_ROWS * NS_1;

    const dim3 blk(256);

    // 1) all casts + transposes
    hipLaunchKernelGGL(prep, dim3(14472), blk, 0, stream,
                       x, x_bf, head_W, headWT, t0_W1, t1_W1, hW1T,
                       t0_W2, t0W2T, t1_W2, t1W2T);

    // 2) packed hidden projections: h_comb[:, :320] = x @ [t0_W1 | t1_W1]
    hipLaunchKernelGGL(gemm_out, dim3(HW1 / 128, N_ROWS / 128), blk, 0, stream,
                       x_bf, IN_F, hW1T, IN_F, IN_F, C0_H + C1_H, h_comb, HW1);

    // 3) sum-exp GEMMs (separate dispatches: homogeneous L2 locality)
    hipLaunchKernelGGL(sumexp_pipe, dim3(NS_H * 32), blk, 0, stream,
                       x_bf, IN_F, headWT, IN_F, IN_F, NCT_H, NT_H, HEAD_N, ps_h, NS_H);
    hipLaunchKernelGGL(sumexp_pipe, dim3(NS_0 * 32), blk, 0, stream,
                       h_comb, HW1, t0W2T, C0_H, C0_H, NCT_0, NT_0, C0_N, ps_0, NS_0);
    hipLaunchKernelGGL(sumexp_c1, dim3(NS_1 * 32), blk, 0, stream,
                       h_comb + C0_H, t1W2T, ps_1);

    // 4) gather + combine, 5) loss
    hipLaunchKernelGGL(gather_combine, dim3(N_ROWS / 4), blk, 0, stream,
                       x_bf, h_comb, headWT, t0W2T, t1W2T, target,
                       ps_h, ps_0, ps_1, out);
    hipLaunchKernelGGL(finalize_loss, dim3(1), blk, 0, stream, out, out + N_ROWS);
}